// Round 5
// baseline (914.096 us; speedup 1.0000x reference)
//
#include <hip/hip_runtime.h>
#include <hip/hip_bf16.h>
#include <cstdint>

// MultiHeadAttention w/ sparsemax: B=2, S=2048, D=1024, H=16, DK=64
#define S_LEN  2048
#define DMODEL 1024
#define NHEAD  16
#define M_ROWS 4096                       // B*S

typedef __attribute__((ext_vector_type(8))) short bf16x8;   // MFMA A/B frag (8 bf16)
typedef __attribute__((ext_vector_type(4))) float f32x4;    // MFMA C/D frag

__device__ __forceinline__ unsigned short f2bf(float f) {
    __hip_bfloat16 h = __float2bfloat16(f);
    return __builtin_bit_cast(unsigned short, h);
}
__device__ __forceinline__ float bf2f(unsigned short u) {
    return __builtin_bit_cast(float, (unsigned)u << 16);
}
__device__ __forceinline__ uint4 pack8(float4 a, float4 b) {
    uint4 u;
    u.x = ((unsigned)f2bf(a.y) << 16) | f2bf(a.x);
    u.y = ((unsigned)f2bf(a.w) << 16) | f2bf(a.z);
    u.z = ((unsigned)f2bf(b.y) << 16) | f2bf(b.x);
    u.w = ((unsigned)f2bf(b.w) << 16) | f2bf(b.z);
    return u;
}

// ---------------------------------------------------------------- wave reduce
__device__ __forceinline__ float wave_sum64(float v) {
    v += __shfl_xor(v, 32, 64); v += __shfl_xor(v, 16, 64);
    v += __shfl_xor(v, 8, 64);  v += __shfl_xor(v, 4, 64);
    v += __shfl_xor(v, 2, 64);  v += __shfl_xor(v, 1, 64);
    return v;
}
__device__ __forceinline__ float wave_max64(float v) {
    v = fmaxf(v, __shfl_xor(v, 32, 64)); v = fmaxf(v, __shfl_xor(v, 16, 64));
    v = fmaxf(v, __shfl_xor(v, 8, 64));  v = fmaxf(v, __shfl_xor(v, 4, 64));
    v = fmaxf(v, __shfl_xor(v, 2, 64));  v = fmaxf(v, __shfl_xor(v, 1, 64));
    return v;
}
__device__ __forceinline__ int lanes_below(unsigned long long m) {
    return __builtin_amdgcn_mbcnt_hi((unsigned)(m >> 32),
           __builtin_amdgcn_mbcnt_lo((unsigned)m, 0));
}

// ------------------------------------- qkv: C = A@W^T + b (fp32 in, bf16 MFMA)
// A[4096,1024] fp32, W[1024,1024] fp32 (NT); inline fp32->bf16 in staging.
// Output row-major bf16 [B,S,DMODEL] via LDS-transpose epilogue (16B stores).
// Q output (which==0) is pre-scaled by 0.125 (= 1/sqrt(DK)); power-of-2 scale
// is a pure exponent shift, so the bf16 rounding is bit-identical.
__global__ __launch_bounds__(256)
void qkv_gemm(const float* __restrict__ xq, const float* __restrict__ xk,
              const float* __restrict__ xv,
              const float* __restrict__ Wq, const float* __restrict__ Wk,
              const float* __restrict__ Wv,
              const float* __restrict__ bq, const float* __restrict__ bk,
              const float* __restrict__ bv,
              unsigned short* __restrict__ Q_bf, unsigned short* __restrict__ K_bf,
              unsigned short* __restrict__ V_bf) {
    const int which = blockIdx.z;
    const float* A    = (which == 0) ? xq : (which == 1) ? xk : xv;
    const float* W    = (which == 0) ? Wq : (which == 1) ? Wk : Wv;
    const float* bias = (which == 0) ? bq : (which == 1) ? bk : bv;
    unsigned short* dst = (which == 0) ? Q_bf : (which == 1) ? K_bf : V_bf;
    const float qscale = (which == 0) ? 0.125f : 1.0f;

    const int row0 = blockIdx.x * 128;
    const int col0 = blockIdx.y * 128;

    __shared__ unsigned short SMEM[10240];    // As(5120) + Bs(5120); epilogue aliases
    unsigned short* As = SMEM;                // stride 40 bf16 (2-way free)
    unsigned short* Bs = SMEM + 5120;

    const int t = threadIdx.x;
    const int wid = t >> 6, lane = t & 63;
    const int wm = wid >> 1, wn = wid & 1;
    const int l = lane & 15, quad = lane >> 4;

    f32x4 acc[4][4];
#pragma unroll
    for (int i = 0; i < 4; ++i)
#pragma unroll
        for (int j = 0; j < 4; ++j) {
            float b_ = bias[col0 + wn * 64 + j * 16 + l];
            acc[i][j] = (f32x4){ b_, b_, b_, b_ };
        }

    for (int k0 = 0; k0 < DMODEL; k0 += 32) {
        uint4 ar[2], br[2];
#pragma unroll
        for (int i = 0; i < 2; ++i) {
            const int c = t + i * 256, r = c >> 2, q = (c & 3) * 8;
            const float* ap = A + (size_t)(row0 + r) * DMODEL + k0 + q;
            const float* wp = W + (size_t)(col0 + r) * DMODEL + k0 + q;
            float4 a0 = *(const float4*)ap, a1 = *(const float4*)(ap + 4);
            float4 w0 = *(const float4*)wp, w1 = *(const float4*)(wp + 4);
            ar[i] = pack8(a0, a1);
            br[i] = pack8(w0, w1);
        }
        __syncthreads();
#pragma unroll
        for (int i = 0; i < 2; ++i) {
            const int c = t + i * 256, r = c >> 2, q = (c & 3) * 8;
            *(uint4*)&As[r * 40 + q] = ar[i];
            *(uint4*)&Bs[r * 40 + q] = br[i];
        }
        __syncthreads();
        bf16x8 a[4], b[4];
#pragma unroll
        for (int i = 0; i < 4; ++i)
            a[i] = *(const bf16x8*)&As[(wm * 64 + i * 16 + l) * 40 + quad * 8];
#pragma unroll
        for (int j = 0; j < 4; ++j)
            b[j] = *(const bf16x8*)&Bs[(wn * 64 + j * 16 + l) * 40 + quad * 8];
#pragma unroll
        for (int i = 0; i < 4; ++i)
#pragma unroll
            for (int j = 0; j < 4; ++j)
                acc[i][j] = __builtin_amdgcn_mfma_f32_16x16x32_bf16(a[i], b[j], acc[i][j], 0, 0, 0);
    }

    // ---- epilogue: acc -> LDS (bf16, stride 72 = 16B-aligned rows) -> uint4 stores
    __syncthreads();
    unsigned short* Cs = SMEM;                // 128*72 = 9216 <= 10240
#pragma unroll 1
    for (int jh = 0; jh < 2; ++jh) {
        if (wn == jh) {
#pragma unroll
            for (int i = 0; i < 4; ++i)
#pragma unroll
                for (int j = 0; j < 4; ++j)
#pragma unroll
                    for (int r = 0; r < 4; ++r)
                        Cs[(wm * 64 + i * 16 + quad * 4 + r) * 72 + j * 16 + l] =
                            f2bf(acc[i][j][r] * qscale);
        }
        __syncthreads();
#pragma unroll
        for (int it = 0; it < 4; ++it) {
            const int idx = t + it * 256;           // 0..1023
            const int row = idx >> 3, c8 = (idx & 7) * 8;
            *(uint4*)(dst + (size_t)(row0 + row) * DMODEL + col0 + jh * 64 + c8) =
                *(const uint4*)&Cs[row * 72 + c8];
        }
        __syncthreads();
    }
}

// ------------------------- fused logits + sparsemax + sparse PV -------------------------
// Block = 8 query rows x 2048 cols of one (b,h); 8 waves (512 thr), wave owns row.
// QK^T in 4 column-quarters streamed through a 16 KB LDS transpose region ->
// z[32]/lane (row max folded into the quarter loop). Candidates (z > max-1)
// compacted into a per-wave LDS list; Newton tau runs on candidates only
// (exact fixpoint early-exit; full-scan fallback preserves exactness).
// Same list drives the sparse V gather (8 V-rows per instruction).
// launch_bounds(512, 6): VGPR cap ~85 so z[32] stays in registers (v4's
// (512,8) cap of 64 forced z into scratch: VGPR_Count=32 + scratch traffic).
__global__ __launch_bounds__(512, 6)
void attn_fused(const unsigned short* __restrict__ Q_bf,
                const unsigned short* __restrict__ K_bf,
                const unsigned short* __restrict__ V_bf,
                float* __restrict__ attn,
                unsigned short* __restrict__ AO_bf) {
    const int t = threadIdx.x;
    const int w = t >> 6, lane = t & 63;
    const int l = lane & 15, quad = lane >> 4;
    const int bh = blockIdx.y, b_ = bh >> 4, h = bh & 15;
    const int r0 = blockIdx.x * 8;

    __shared__ uint2 List[8 * 512];    // 32 KB; first 16 KB aliased as transpose buf
    float* LDSf = (float*)List;

    // ---- Q fragments: A rows l&7 -> C rows 0..7 valid (8..15 duplicates)
    const unsigned short* Qp =
        Q_bf + ((size_t)(b_ * S_LEN + r0 + (l & 7))) * DMODEL + h * 64 + quad * 8;
    const bf16x8 a0 = *(const bf16x8*)Qp;
    const bf16x8 a1 = *(const bf16x8*)(Qp + 32);

    float z[32];
    float m = -__builtin_inff();
    // ---- QK^T in 4 column-quarters; wave w covers cols q*512 + [w*64, w*64+64)
#pragma unroll
    for (int q = 0; q < 4; ++q) {
        const unsigned short* Kb =
            K_bf + ((size_t)(b_ * S_LEN + q * 512 + w * 64 + l)) * DMODEL
            + h * 64 + quad * 8;
        f32x4 acc[4];
#pragma unroll
        for (int ct = 0; ct < 4; ++ct) {
            const unsigned short* Kp = Kb + (size_t)(ct * 16) * DMODEL;
            const bf16x8 b0 = *(const bf16x8*)Kp;
            const bf16x8 b1 = *(const bf16x8*)(Kp + 32);
            f32x4 c = {};
            c = __builtin_amdgcn_mfma_f32_16x16x32_bf16(a0, b0, c, 0, 0, 0);
            c = __builtin_amdgcn_mfma_f32_16x16x32_bf16(a1, b1, c, 0, 0, 0);
            acc[ct] = c;                           // Q pre-scaled by 1/8 in qkv
        }
        // transpose: rows = quad*4+r (quads 0,1 hold real rows 0..7)
        if (quad < 2) {
#pragma unroll
            for (int ct = 0; ct < 4; ++ct)
#pragma unroll
                for (int r = 0; r < 4; ++r)
                    LDSf[(quad * 4 + r) * 512 + w * 64 + ct * 16 + l] = acc[ct][r];
        }
        __syncthreads();
#pragma unroll
        for (int j = 0; j < 8; ++j) {
            z[q * 8 + j] = LDSf[w * 512 + j * 64 + lane];
            m = fmaxf(m, z[q * 8 + j]);            // running row max (z hot)
        }
        __syncthreads();
    }

    // ---- row max; candidate threshold thr = m - 1 (tau* >= m-1 always)
    m = wave_max64(m);
    const float thr = m - 1.0f;

    // ---- candidate compaction: (col, z) with z > thr, per-wave list
    uint2* list = List + w * 512;
    int cnt = 0;
#pragma unroll
    for (int jj = 0; jj < 32; ++jj) {
        const float zv = z[jj];
        const unsigned long long mk = __ballot(zv > thr);
        if (zv > thr) {
            const int pos = cnt + lanes_below(mk);
            if (pos < 512)
                list[pos] = (uint2){ (unsigned)((jj >> 3) * 512 + (jj & 7) * 64 + lane),
                                     __builtin_bit_cast(unsigned, zv) };
        }
        cnt += __popcll(mk);
    }
    __threadfence_block();

    // ---- Newton waterfilling on candidates (common) or full scan (fallback)
    float tau = thr;
    if (cnt <= 256) {
        const float NEG = -__builtin_inff();
        const float zc0 = (lane < cnt)
            ? __builtin_bit_cast(float, list[lane].y) : NEG;
        const float zc1 = (64 + lane < cnt)
            ? __builtin_bit_cast(float, list[64 + lane].y) : NEG;
        const float zc2 = (128 + lane < cnt)
            ? __builtin_bit_cast(float, list[128 + lane].y) : NEG;
        const float zc3 = (192 + lane < cnt)
            ? __builtin_bit_cast(float, list[192 + lane].y) : NEG;
#pragma unroll 1
        for (int it = 0; it < 12; ++it) {
            float ss = 0.0f, kk = 0.0f;
            if (zc0 > tau) { ss += zc0; kk += 1.0f; }
            if (zc1 > tau) { ss += zc1; kk += 1.0f; }
            if (zc2 > tau) { ss += zc2; kk += 1.0f; }
            if (zc3 > tau) { ss += zc3; kk += 1.0f; }
            ss = wave_sum64(ss); kk = wave_sum64(kk);
            const float tn = (ss - 1.0f) / kk;     // uniform across wave
            if (tn == tau) break;                  // support stabilized -> exact
            tau = tn;
        }
    } else {
#pragma unroll 1
        for (int it = 0; it < 8; ++it) {
            float ss = 0.0f, kk = 0.0f;
#pragma unroll
            for (int j = 0; j < 32; ++j)
                if (z[j] > tau) { ss += z[j]; kk += 1.0f; }
            ss = wave_sum64(ss); kk = wave_sum64(kk);
            const float tn = (ss - 1.0f) / kk;
            if (tn == tau) break;
            tau = tn;
        }
        // recompact: support only (z > tau), same (col, z) entry format
        cnt = 0;
#pragma unroll
        for (int jj = 0; jj < 32; ++jj) {
            const float zv = z[jj];
            const unsigned long long mk = __ballot(zv > tau);
            if (zv > tau) {
                const int pos = cnt + lanes_below(mk);
                if (pos < 512)
                    list[pos] = (uint2){ (unsigned)((jj >> 3) * 512 + (jj & 7) * 64 + lane),
                                         __builtin_bit_cast(unsigned, zv) };
            }
            cnt += __popcll(mk);
        }
        __threadfence_block();
    }
    if (cnt > 504) cnt = 504;                      // keep pad + reads in bounds

    // ---- p = max(z - tau, 0); coalesced nontemporal fp32 attn row store
    float* ap = attn + (size_t)bh * S_LEN * S_LEN + (size_t)(r0 + w) * S_LEN;
#pragma unroll
    for (int jj = 0; jj < 32; ++jj) {
        const float pv = fmaxf(z[jj] - tau, 0.0f);
        __builtin_nontemporal_store(pv, ap + (jj >> 3) * 512 + (jj & 7) * 64 + lane);
    }

    // ---- pad list to a multiple of 8 with -inf entries (guard-free gather)
    if (lane < 8)
        list[cnt + lane] = (uint2){ 0u, 0xff800000u };   // z = -inf -> p = 0
    __threadfence_block();

    // ---- gather: 8 V-rows per iteration (8-lane subgroups, uint4 each)
    const unsigned short* Vh = V_bf + ((size_t)b_ * S_LEN) * DMODEL + h * 64;
    const int sub = lane >> 3, dbase = (lane & 7) * 8;
    float acc8[8] = {};
    const int gmax = (cnt + 7) >> 3;
#pragma unroll 2
    for (int g = 0; g < gmax; ++g) {
        const uint2 e = list[g * 8 + sub];
        const float p = fmaxf(__builtin_bit_cast(float, e.y) - tau, 0.0f);
        const uint4 vv = *(const uint4*)(Vh + ((size_t)e.x) * DMODEL + dbase);
        acc8[0] += p * bf2f((unsigned short)(vv.x & 0xffff));
        acc8[1] += p * bf2f((unsigned short)(vv.x >> 16));
        acc8[2] += p * bf2f((unsigned short)(vv.y & 0xffff));
        acc8[3] += p * bf2f((unsigned short)(vv.y >> 16));
        acc8[4] += p * bf2f((unsigned short)(vv.z & 0xffff));
        acc8[5] += p * bf2f((unsigned short)(vv.z >> 16));
        acc8[6] += p * bf2f((unsigned short)(vv.w & 0xffff));
        acc8[7] += p * bf2f((unsigned short)(vv.w >> 16));
    }
    // reduce across the 8 subgroups (stride-8 butterfly)
#pragma unroll
    for (int d = 0; d < 8; ++d) {
        acc8[d] += __shfl_xor(acc8[d], 8, 64);
        acc8[d] += __shfl_xor(acc8[d], 16, 64);
        acc8[d] += __shfl_xor(acc8[d], 32, 64);
    }
    if (lane < 8) {
        union { unsigned short u[8]; uint4 v; } o;
#pragma unroll
        for (int d = 0; d < 8; ++d) o.u[d] = f2bf(acc8[d]);
        *(uint4*)(AO_bf + ((size_t)(b_ * S_LEN + r0 + w)) * DMODEL
                  + h * 64 + lane * 8) = o.v;
    }
}

// ---------------------- out = AO @ Wfc^T + bfc (bf16 A, fp32 W inline-cast)
__global__ __launch_bounds__(256)
void fc_gemm(const unsigned short* __restrict__ AO_bf,
             const float* __restrict__ Wfc,
             const float* __restrict__ bfc, float* __restrict__ out) {
    const int row0 = blockIdx.x * 128;
    const int col0 = blockIdx.y * 128;

    __shared__ unsigned short As[128 * 40];
    __shared__ unsigned short Bs[128 * 40];

    const int t = threadIdx.x;
    const int wid = t >> 6, lane = t & 63;
    const int wm = wid >> 1, wn = wid & 1;
    const int l = lane & 15, quad = lane >> 4;

    f32x4 acc[4][4];
#pragma unroll
    for (int i = 0; i < 4; ++i)
#pragma unroll
        for (int j = 0; j < 4; ++j) {
            float b_ = bfc[col0 + wn * 64 + j * 16 + l];
            acc[i][j] = (f32x4){ b_, b_, b_, b_ };
        }

    for (int k0 = 0; k0 < DMODEL; k0 += 32) {
        uint4 ar[2], br[2];
#pragma unroll
        for (int i = 0; i < 2; ++i) {
            const int c = t + i * 256, r = c >> 2, q = (c & 3) * 8;
            ar[i] = *(const uint4*)(AO_bf + (size_t)(row0 + r) * DMODEL + k0 + q);
            const float* wp = Wfc + (size_t)(col0 + r) * DMODEL + k0 + q;
            float4 w0 = *(const float4*)wp, w1 = *(const float4*)(wp + 4);
            br[i] = pack8(w0, w1);
        }
        __syncthreads();
#pragma unroll
        for (int i = 0; i < 2; ++i) {
            const int c = t + i * 256, r = c >> 2, q = (c & 3) * 8;
            *(uint4*)&As[r * 40 + q] = ar[i];
            *(uint4*)&Bs[r * 40 + q] = br[i];
        }
        __syncthreads();
        bf16x8 a[4], b[4];
#pragma unroll
        for (int i = 0; i < 4; ++i)
            a[i] = *(const bf16x8*)&As[(wm * 64 + i * 16 + l) * 40 + quad * 8];
#pragma unroll
        for (int j = 0; j < 4; ++j)
            b[j] = *(const bf16x8*)&Bs[(wn * 64 + j * 16 + l) * 40 + quad * 8];
#pragma unroll
        for (int i = 0; i < 4; ++i)
#pragma unroll
            for (int j = 0; j < 4; ++j)
                acc[i][j] = __builtin_amdgcn_mfma_f32_16x16x32_bf16(a[i], b[j], acc[i][j], 0, 0, 0);
    }

#pragma unroll
    for (int i = 0; i < 4; ++i)
#pragma unroll
        for (int r = 0; r < 4; ++r) {
            const int m = row0 + wm * 64 + i * 16 + quad * 4 + r;
#pragma unroll
            for (int j = 0; j < 4; ++j) {
                const int n = col0 + wn * 64 + j * 16 + l;
                out[(size_t)m * DMODEL + n] = acc[i][j][r];
            }
        }
}

// ----------------------------------------------------------------------- launch
extern "C" void kernel_launch(void* const* d_in, const int* in_sizes, int n_in,
                              void* d_out, int out_size, void* d_ws, size_t ws_size,
                              hipStream_t stream) {
    const float* q   = (const float*)d_in[0];
    const float* k   = (const float*)d_in[1];
    const float* v   = (const float*)d_in[2];
    const float* Wq  = (const float*)d_in[3];
    const float* bq  = (const float*)d_in[4];
    const float* Wk  = (const float*)d_in[5];
    const float* bk  = (const float*)d_in[6];
    const float* Wv  = (const float*)d_in[7];
    const float* bv  = (const float*)d_in[8];
    const float* Wfc = (const float*)d_in[9];
    const float* bfc = (const float*)d_in[10];

    float* out  = (float*)d_out;                       // [B,S,D] fp32
    float* attn = out + (size_t)M_ROWS * DMODEL;       // [B,H,S,S] fp32

    // workspace: Q_bf [0,8M), K_bf [8,16M), V_bf [16,24M), AO_bf [24,32M)
    char* ws = (char*)d_ws;
    unsigned short* Q_bf  = (unsigned short*)ws;
    unsigned short* K_bf  = (unsigned short*)(ws + (8u << 20));
    unsigned short* V_bf  = (unsigned short*)(ws + (16u << 20));
    unsigned short* AO_bf = (unsigned short*)(ws + (24u << 20));

    qkv_gemm<<<dim3(32, 8, 3), 256, 0, stream>>>(q, k, v, Wq, Wk, Wv,
                                                  bq, bk, bv, Q_bf, K_bf, V_bf);
    attn_fused<<<dim3(S_LEN / 8, 32), 512, 0, stream>>>(Q_bf, K_bf, V_bf, attn, AO_bf);
    fc_gemm<<<dim3(32, 8), 256, 0, stream>>>(AO_bf, Wfc, bfc, out);
}